// Round 6
// baseline (490.292 us; speedup 1.0000x reference)
//
#include <hip/hip_runtime.h>
#include <hip/hip_bf16.h>
#include <math.h>

#define NE_N 50000
#define NM_N 50000
#define NEDGE 500000

typedef __attribute__((ext_vector_type(8))) short bf16x8;
typedef __attribute__((ext_vector_type(4))) float f32x4;

__device__ __forceinline__ ushort f2bf(float f) {
  uint u = __float_as_uint(f);
  u += 0x7fffu + ((u >> 16) & 1u);   // RNE
  return (ushort)(u >> 16);
}
__device__ __forceinline__ float bfl(uint u) { return __uint_as_float(u << 16); }
__device__ __forceinline__ float bfh(uint u) { return __uint_as_float(u & 0xffff0000u); }

struct GArgs {
  const ushort* A; const float* Af; const ushort* Wt; const float* bias;
  ushort* Cb; const float* aV; float* alsOut; const float* Vald; float* aldOut;
  int M; int act;
};
struct AArgs {
  const ushort* hs; const float4* p; const int* offs; const int* ssrc;
  const float* bias; float* out; ushort* outB; const float* Vald; float* aldOut;
  int Ndst;
};

// ---- cast + transpose 7 GEMM weights: Wt[n][k] = bf16(W[k][n]) -----------
__global__ __launch_bounds__(256) void wcast_k(const float* W0, const float* W1,
    const float* W2, const float* W3, const float* W4, const float* W5,
    const float* W6, ushort* __restrict__ Wt) {
  __shared__ float T[128][129];
  const float* W;
  switch (blockIdx.x) {
    case 0: W = W0; break; case 1: W = W1; break; case 2: W = W2; break;
    case 3: W = W3; break; case 4: W = W4; break; case 5: W = W5; break;
    default: W = W6;
  }
  int tid = threadIdx.x;
  for (int i = tid; i < 16384; i += 256) T[i >> 7][i & 127] = W[i];
  __syncthreads();
  uint* o = (uint*)(Wt + (size_t)blockIdx.x * 16384);
  for (int i = tid; i < 8192; i += 256) {
    int n = i >> 6, k2 = (i & 63) << 1;
    o[i] = (uint)f2bf(T[k2][n]) | ((uint)f2bf(T[k2 + 1][n]) << 16);
  }
}

// ---- V[k,h] folds for the 4 dst attention vectors -------------------------
__global__ void vfold4_k(const float* __restrict__ Wem, const float* __restrict__ aem,
                         const float* __restrict__ Wme, const float* __restrict__ ame,
                         float* __restrict__ Vbase) {
  int idx = blockIdx.x;
  int layer = idx >> 1, et = idx & 1;
  const float* W = (et ? Wme : Wem) + layer * 16384;
  const float* a = (et ? ame : aem) + layer * 128;
  float* V = Vbase + idx * 512;
  int t = threadIdx.x;  // 512
  int k = t >> 2, h = t & 3;
  float s = 0.f;
#pragma unroll
  for (int d = 0; d < 32; ++d) s += W[k * 128 + h * 32 + d] * a[h * 32 + d];
  V[k * 4 + h] = s;
}

// ---- paired MFMA bf16 GEMM ------------------------------------------------
__global__ __launch_bounds__(256) void mgemm2_k(GArgs ga, GArgs gb, int nA) {
  const bool isA = (int)blockIdx.x < nA;
  GArgs g = isA ? ga : gb;
  const int bid = isA ? blockIdx.x : blockIdx.x - nA;
  __shared__ ushort smem[32768];
  char* sA = (char*)smem;
  char* sW = (char*)(smem + 16384);
  const int tid = threadIdx.x;
  const int row0 = bid * 128;
#pragma unroll
  for (int i = 0; i < 8; ++i) {
    int l = (tid + i * 256) << 4;
    int rl = l >> 8;
    int rg = row0 + rl; rg = rg < g.M ? rg : g.M - 1;
    if (g.Af) {
      int c0f = (l & 255) >> 1;
      float4 a = *(const float4*)&g.Af[(size_t)rg * 128 + c0f];
      float4 b = *(const float4*)&g.Af[(size_t)rg * 128 + c0f + 4];
      ushort r[8] = {f2bf(a.x), f2bf(a.y), f2bf(a.z), f2bf(a.w),
                     f2bf(b.x), f2bf(b.y), f2bf(b.z), f2bf(b.w)};
      *(uint4*)(sA + (l ^ ((rl & 7) << 4))) = *(uint4*)r;
    } else {
      uint4 v = *(const uint4*)((const char*)g.A + (size_t)rg * 256 + (l & 255));
      *(uint4*)(sA + (l ^ ((rl & 7) << 4))) = v;
    }
    uint4 w = *(const uint4*)((const char*)g.Wt + l);
    *(uint4*)(sW + (l ^ ((rl & 7) << 4))) = w;
  }
  __syncthreads();
  const int lane = tid & 63, wid = tid >> 6;
  const int l15 = lane & 15, lq = lane >> 4;
  const int wm = wid * 32;
  f32x4 acc[2][8];
#pragma unroll
  for (int mt = 0; mt < 2; ++mt)
#pragma unroll
    for (int nt = 0; nt < 8; ++nt) {
      f32x4 z = {0.f, 0.f, 0.f, 0.f};
      acc[mt][nt] = z;
    }
#pragma unroll
  for (int ks = 0; ks < 4; ++ks) {
    int r0r = wm + l15;
    int o0 = (r0r << 8) + (ks << 6) + (lq << 4);
    bf16x8 af0 = *(const bf16x8*)(sA + (o0 ^ ((r0r & 7) << 4)));
    int r1r = r0r + 16;
    int o1 = (r1r << 8) + (ks << 6) + (lq << 4);
    bf16x8 af1 = *(const bf16x8*)(sA + (o1 ^ ((r1r & 7) << 4)));
#pragma unroll
    for (int nt = 0; nt < 8; ++nt) {
      int c = (nt << 4) + l15;
      int ob = (c << 8) + (ks << 6) + (lq << 4);
      bf16x8 bf = *(const bf16x8*)(sW + (ob ^ ((c & 7) << 4)));
      acc[0][nt] = __builtin_amdgcn_mfma_f32_16x16x32_bf16(af0, bf, acc[0][nt], 0, 0, 0);
      acc[1][nt] = __builtin_amdgcn_mfma_f32_16x16x32_bf16(af1, bf, acc[1][nt], 0, 0, 0);
    }
  }
  float aVv[8], bv[8];
  f32x4 vv[8];
#pragma unroll
  for (int nt = 0; nt < 8; ++nt) {
    int c = (nt << 4) + l15;
    aVv[nt] = g.aV ? g.aV[c] : 0.f;
    bv[nt] = g.bias ? g.bias[c] : 0.f;
    if (g.Vald) vv[nt] = *(const f32x4*)&g.Vald[c * 4];
  }
  if (g.aV) {
#pragma unroll
    for (int mt = 0; mt < 2; ++mt)
#pragma unroll
      for (int rg = 0; rg < 4; ++rg) {
        float p0 = fmaf(acc[mt][0][rg], aVv[0], acc[mt][1][rg] * aVv[1]);
        float p1 = fmaf(acc[mt][2][rg], aVv[2], acc[mt][3][rg] * aVv[3]);
        float p2 = fmaf(acc[mt][4][rg], aVv[4], acc[mt][5][rg] * aVv[5]);
        float p3 = fmaf(acc[mt][6][rg], aVv[6], acc[mt][7][rg] * aVv[7]);
#pragma unroll
        for (int off = 1; off < 16; off <<= 1) {
          p0 += __shfl_xor(p0, off, 64);
          p1 += __shfl_xor(p1, off, 64);
          p2 += __shfl_xor(p2, off, 64);
          p3 += __shfl_xor(p3, off, 64);
        }
        int r = row0 + wm + mt * 16 + lq * 4 + rg;
        if (l15 == 0 && r < g.M)
          *(float4*)&g.alsOut[(size_t)r * 4] = make_float4(p0, p1, p2, p3);
      }
  }
#pragma unroll
  for (int mt = 0; mt < 2; ++mt)
#pragma unroll
    for (int nt = 0; nt < 8; ++nt)
#pragma unroll
      for (int rg = 0; rg < 4; ++rg) {
        float v = acc[mt][nt][rg] + bv[nt];
        if (g.act) v = fmaxf(v, 0.f);
        acc[mt][nt][rg] = v;
      }
  if (g.Vald) {
#pragma unroll
    for (int mt = 0; mt < 2; ++mt)
#pragma unroll
      for (int rg = 0; rg < 4; ++rg) {
        float q0 = 0.f, q1 = 0.f, q2 = 0.f, q3 = 0.f;
#pragma unroll
        for (int nt = 0; nt < 8; ++nt) {
          float v = acc[mt][nt][rg];
          q0 = fmaf(v, vv[nt][0], q0);
          q1 = fmaf(v, vv[nt][1], q1);
          q2 = fmaf(v, vv[nt][2], q2);
          q3 = fmaf(v, vv[nt][3], q3);
        }
#pragma unroll
        for (int off = 1; off < 16; off <<= 1) {
          q0 += __shfl_xor(q0, off, 64);
          q1 += __shfl_xor(q1, off, 64);
          q2 += __shfl_xor(q2, off, 64);
          q3 += __shfl_xor(q3, off, 64);
        }
        int r = row0 + wm + mt * 16 + lq * 4 + rg;
        if (l15 == 0 && r < g.M)
          *(float4*)&g.aldOut[(size_t)r * 4] = make_float4(q0, q1, q2, q3);
      }
  }
  __syncthreads();
#pragma unroll
  for (int mt = 0; mt < 2; ++mt)
#pragma unroll
    for (int nt = 0; nt < 8; ++nt)
#pragma unroll
      for (int rg = 0; rg < 4; ++rg) {
        int r = wm + mt * 16 + lq * 4 + rg;
        int c = (nt << 4) + l15;
        *(ushort*)(sA + ((r << 8) + ((c << 1) ^ ((r & 7) << 4)))) =
            f2bf(acc[mt][nt][rg]);
      }
  __syncthreads();
#pragma unroll
  for (int i = 0; i < 8; ++i) {
    int l = (tid + i * 256) << 4;
    int rl = l >> 8;
    if (row0 + rl < g.M)
      *(uint4*)((char*)g.Cb + (size_t)row0 * 256 + l) =
          *(const uint4*)(sA + (l ^ ((rl & 7) << 4)));
  }
}

// ---- unified counting sort over both edge types (100k buckets) ------------
__global__ void hist2_k(const int* __restrict__ de, const int* __restrict__ dm,
                        int* __restrict__ cnt) {
  int e = blockIdx.x * 256 + threadIdx.x;
  if (e < NEDGE) atomicAdd(&cnt[de[e]], 1);
  else if (e < 2 * NEDGE) atomicAdd(&cnt[NM_N + dm[e - NEDGE]], 1);
}

__global__ __launch_bounds__(256) void scanA_k(const int* __restrict__ cnt,
                                               int* __restrict__ offs,
                                               int* __restrict__ sums, int n) {
  __shared__ int ts[256];
  int tid = threadIdx.x;
  int base = blockIdx.x * 4096 + tid * 16;
  int v[16];
  int s = 0;
#pragma unroll
  for (int i = 0; i < 16; ++i) {
    v[i] = (base + i < n) ? cnt[base + i] : 0;
    s += v[i];
  }
  ts[tid] = s;
  __syncthreads();
  for (int off = 1; off < 256; off <<= 1) {
    int t = (tid >= off) ? ts[tid - off] : 0;
    __syncthreads();
    ts[tid] += t;
    __syncthreads();
  }
  int run = ts[tid] - s;
#pragma unroll
  for (int i = 0; i < 16; ++i) {
    if (base + i < n) offs[base + i] = run;
    run += v[i];
  }
  if (tid == 255) sums[blockIdx.x] = ts[255];
}

__global__ void scanB_k(int* __restrict__ sums, int nchunk) {
  if (threadIdx.x == 0) {
    int acc = 0;
    for (int i = 0; i < nchunk; ++i) {
      int t = sums[i];
      sums[i] = acc;
      acc += t;
    }
    sums[nchunk] = acc;
  }
}

__global__ void scanC_k(int* __restrict__ offs, const int* __restrict__ sums, int n) {
  int i = blockIdx.x * blockDim.x + threadIdx.x;
  if (i < n) offs[i] += sums[i >> 12];
  if (i == 0) offs[n] = sums[(n + 4095) >> 12];
}

__global__ void scatter2_k(const int* __restrict__ se, const int* __restrict__ de,
                           const int* __restrict__ sm, const int* __restrict__ dm,
                           const int* __restrict__ offs, int* __restrict__ cur,
                           int* __restrict__ ssrc, int* __restrict__ sdst) {
  int e = blockIdx.x * 256 + threadIdx.x;
  if (e >= 2 * NEDGE) return;
  int s, dl, db;
  if (e < NEDGE) { s = se[e]; dl = de[e]; db = dl; }
  else { s = sm[e - NEDGE]; dl = dm[e - NEDGE]; db = NM_N + dl; }
  int pos = offs[db] + atomicAdd(&cur[db], 1);
  ssrc[pos] = s;
  sdst[pos] = dl;
}

// ---- edge-parallel softmax weights: p[e] = exp(leaky(als[s]+ald[d])) ------
__global__ __launch_bounds__(256) void pexp_k(const int* __restrict__ ssrc,
    const int* __restrict__ sdst,
    const float* __restrict__ alsA, const float* __restrict__ aldA,
    const float* __restrict__ alsB, const float* __restrict__ aldB,
    float4* __restrict__ p) {
  int e = blockIdx.x * 256 + threadIdx.x;
  if (e >= 2 * NEDGE) return;
  bool em = e < NEDGE;  // em edges occupy positions [0, NEDGE)
  const float* als = em ? alsA : alsB;
  const float* ald = em ? aldA : aldB;
  int s = ssrc[e], d = sdst[e];
  float4 a = *(const float4*)&als[(size_t)s * 4];
  float4 b = *(const float4*)&ald[(size_t)d * 4];
  float e0 = a.x + b.x, e1 = a.y + b.y, e2 = a.z + b.z, e3 = a.w + b.w;
  e0 = (e0 > 0.f) ? e0 : 0.2f * e0;
  e1 = (e1 > 0.f) ? e1 : 0.2f * e1;
  e2 = (e2 > 0.f) ? e2 : 0.2f * e2;
  e3 = (e3 > 0.f) ? e3 : 0.2f * e3;
  p[e] = make_float4(__expf(e0), __expf(e1), __expf(e2), __expf(e3));
}

// ---- paired per-dst aggregation: gather hs, weight by p, +bias +ELU -------
__global__ __launch_bounds__(256) void agg2_k(AArgs aa, AArgs ab, int nA) {
  const bool isA = (int)blockIdx.x < nA;
  AArgs g = isA ? aa : ab;
  const int bid = isA ? blockIdx.x : blockIdx.x - nA;
  const int lane = threadIdx.x & 63;
  const int n = (bid * 256 + (int)threadIdx.x) >> 6;
  if (n >= g.Ndst) return;
  const int h = lane >> 4;
  const uint* hsu = (const uint*)g.hs;
  const int i0 = g.offs[n], i1 = g.offs[n + 1];
  float den = 0.f, acc0 = 0.f, acc1 = 0.f;
  int i = i0;
  for (; i + 8 <= i1; i += 8) {
    int ss[8];
    float pv[8];
#pragma unroll
    for (int k = 0; k < 8; ++k) {
      ss[k] = g.ssrc[i + k];
      float4 pq = g.p[i + k];
      float lo = (h & 1) ? pq.y : pq.x;
      float hi = (h & 1) ? pq.w : pq.z;
      pv[k] = (h & 2) ? hi : lo;
    }
#pragma unroll
    for (int k = 0; k < 8; ++k) {
      uint u = hsu[(size_t)ss[k] * 64 + lane];
      acc0 = fmaf(pv[k], bfl(u), acc0);
      acc1 = fmaf(pv[k], bfh(u), acc1);
      den += pv[k];
    }
  }
  for (; i < i1; ++i) {
    int s0 = g.ssrc[i];
    float4 pq = g.p[i];
    float lo = (h & 1) ? pq.y : pq.x;
    float hi = (h & 1) ? pq.w : pq.z;
    float pvv = (h & 2) ? hi : lo;
    uint u = hsu[(size_t)s0 * 64 + lane];
    acc0 = fmaf(pvv, bfl(u), acc0);
    acc1 = fmaf(pvv, bfh(u), acc1);
    den += pvv;
  }
  const float inv = 1.f / (den + 1e-16f);
  float r0 = acc0 * inv + g.bias[2 * lane];
  float r1 = acc1 * inv + g.bias[2 * lane + 1];
  r0 = (r0 > 0.f) ? r0 : expm1f(r0);  // ELU
  r1 = (r1 > 0.f) ? r1 : expm1f(r1);
  if (g.out)
    *(float2*)&g.out[(size_t)n * 128 + 2 * lane] = make_float2(r0, r1);
  if (g.outB)
    ((uint*)g.outB)[(size_t)n * 64 + lane] = (uint)f2bf(r0) | ((uint)f2bf(r1) << 16);
  if (g.Vald) {
    const float4 w0 = *(const float4*)&g.Vald[(2 * lane) * 4];
    const float4 w1 = *(const float4*)&g.Vald[(2 * lane + 1) * 4];
    float t0 = fmaf(r0, w0.x, r1 * w1.x);
    float t1 = fmaf(r0, w0.y, r1 * w1.y);
    float t2 = fmaf(r0, w0.z, r1 * w1.z);
    float t3 = fmaf(r0, w0.w, r1 * w1.w);
#pragma unroll
    for (int off = 1; off < 64; off <<= 1) {
      t0 += __shfl_xor(t0, off, 64);
      t1 += __shfl_xor(t1, off, 64);
      t2 += __shfl_xor(t2, off, 64);
      t3 += __shfl_xor(t3, off, 64);
    }
    if (lane == 0)
      *(float4*)&g.aldOut[(size_t)n * 4] = make_float4(t0, t1, t2, t3);
  }
}

// ---- fused regressor tail: pred = relu(h1(bf16)@W2+b2) @ W3 + b3 ----------
__global__ __launch_bounds__(256) void regfuse_k(const ushort* __restrict__ h1,
    const float* __restrict__ W2, const float* __restrict__ b2,
    const float* __restrict__ W3, const float* __restrict__ b3,
    float* __restrict__ pred, int M) {
  __shared__ float X[64][132];
  const int tid = threadIdx.x;
  const int row0 = blockIdx.x * 64;
#pragma unroll
  for (int i = 0; i < 4; ++i) {
    int q = tid + i * 256;
    int r = q >> 4, c8 = (q & 15) << 3;
    uint4 v = make_uint4(0, 0, 0, 0);
    if (row0 + r < M) v = *(const uint4*)&h1[(size_t)(row0 + r) * 128 + c8];
    X[r][c8 + 0] = bfl(v.x); X[r][c8 + 1] = bfh(v.x);
    X[r][c8 + 2] = bfl(v.y); X[r][c8 + 3] = bfh(v.y);
    X[r][c8 + 4] = bfl(v.z); X[r][c8 + 5] = bfh(v.z);
    X[r][c8 + 6] = bfl(v.w); X[r][c8 + 7] = bfh(v.w);
  }
  __syncthreads();
  const int cg = tid & 15, rq = tid >> 4;
  const int c0 = cg * 4;
  float acc[4][4];
#pragma unroll
  for (int s = 0; s < 4; ++s)
#pragma unroll
    for (int j = 0; j < 4; ++j) acc[s][j] = 0.f;
#pragma unroll 4
  for (int k = 0; k < 128; ++k) {
    float xv[4] = {X[rq][k], X[rq + 16][k], X[rq + 32][k], X[rq + 48][k]};
    float4 w = *(const float4*)&W2[k * 64 + c0];
#pragma unroll
    for (int s = 0; s < 4; ++s) {
      acc[s][0] = fmaf(xv[s], w.x, acc[s][0]);
      acc[s][1] = fmaf(xv[s], w.y, acc[s][1]);
      acc[s][2] = fmaf(xv[s], w.z, acc[s][2]);
      acc[s][3] = fmaf(xv[s], w.w, acc[s][3]);
    }
  }
  float4 bq = *(const float4*)&b2[c0];
  float4 w3 = *(const float4*)&W3[c0];
  float bb[4] = {bq.x, bq.y, bq.z, bq.w};
  float ww[4] = {w3.x, w3.y, w3.z, w3.w};
#pragma unroll
  for (int s = 0; s < 4; ++s) {
    float v = 0.f;
#pragma unroll
    for (int j = 0; j < 4; ++j) v = fmaf(fmaxf(acc[s][j] + bb[j], 0.f), ww[j], v);
    v += __shfl_xor(v, 1, 64);
    v += __shfl_xor(v, 2, 64);
    v += __shfl_xor(v, 4, 64);
    v += __shfl_xor(v, 8, 64);
    int r = row0 + rq + 16 * s;
    if (cg == 0 && r < M) pred[r] = v + b3[0];
  }
}

extern "C" void kernel_launch(void* const* d_in, const int* in_sizes, int n_in,
                              void* d_out, int out_size, void* d_ws, size_t ws_size,
                              hipStream_t stream) {
  const float* x_exp   = (const float*)d_in[0];
  const float* x_mat   = (const float*)d_in[1];
  const int*   ei_em   = (const int*)d_in[2];
  const int*   ei_me   = (const int*)d_in[3];
  const float* Win_exp = (const float*)d_in[4];
  const float* bin_exp = (const float*)d_in[5];
  const float* Win_mat = (const float*)d_in[6];
  const float* bin_mat = (const float*)d_in[7];
  const float* Wsrc_em = (const float*)d_in[8];
  const float* Wdst_em = (const float*)d_in[9];
  const float* asrc_em = (const float*)d_in[10];
  const float* adst_em = (const float*)d_in[11];
  const float* b_em    = (const float*)d_in[12];
  const float* Wsrc_me = (const float*)d_in[13];
  const float* Wdst_me = (const float*)d_in[14];
  const float* asrc_me = (const float*)d_in[15];
  const float* adst_me = (const float*)d_in[16];
  const float* b_me    = (const float*)d_in[17];
  const float* Wr1     = (const float*)d_in[18];
  const float* br1     = (const float*)d_in[19];
  const float* Wr2     = (const float*)d_in[20];
  const float* br2     = (const float*)d_in[21];
  const float* Wr3     = (const float*)d_in[22];
  const float* br3     = (const float*)d_in[23];

  float* pred = (float*)d_out;
  float* heO  = pred + NE_N;
  float* hmO  = heO + (size_t)NE_N * 128;

  ushort* bufA = (ushort*)d_ws;                   // 4 x 12.8MB bf16 buffers
  ushort* bufB = bufA + (size_t)6400000;
  ushort* bufC = bufB + (size_t)6400000;
  ushort* bufD = bufC + (size_t)6400000;
  ushort* Wt   = bufD + (size_t)6400000;          // 7 x 16384 bf16
  float4* p    = (float4*)(Wt + 7 * 16384);       // 1M float4 (16MB)
  float* alsE  = (float*)(p + 1000000);           // als for em convs (src=exp)
  float* alsM  = alsE + 200000;                   // als for me convs (src=mat)
  float* aldE  = alsM + 200000;
  float* aldM  = aldE + 200000;
  float* Vb    = aldM + 200000;                   // 4 x 512
  int*   sums  = (int*)(Vb + 2048);               // 32
  int*   cnt   = sums + 32;                       // 100k buckets
  int*   offs  = cnt + 100000;                    // 100001
  int*   ssrc  = offs + 100002;                   // 1M
  int*   sdst  = ssrc + 1000000;                  // 1M

  const int* se = ei_em;
  const int* de = ei_em + NEDGE;
  const int* sm = ei_me;
  const int* dm = ei_me + NEDGE;

  const int gE2 = (2 * NEDGE + 255) / 256;
  const int gWave = (NE_N + 3) / 4;     // 12501
  const int gGemm = (NE_N + 127) / 128; // 391
  const int nChunk = (100000 + 4095) / 4096;  // 25

  // ---- unified counting sort (both edge types, 100k buckets) ----
  hipMemsetAsync(cnt, 0, 100000 * sizeof(int), stream);
  hist2_k<<<gE2, 256, 0, stream>>>(de, dm, cnt);
  scanA_k<<<nChunk, 256, 0, stream>>>(cnt, offs, sums, 100000);
  scanB_k<<<1, 64, 0, stream>>>(sums, nChunk);
  scanC_k<<<(100000 + 255) / 256, 256, 0, stream>>>(offs, sums, 100000);
  hipMemsetAsync(cnt, 0, 100000 * sizeof(int), stream);
  scatter2_k<<<gE2, 256, 0, stream>>>(se, de, sm, dm, offs, cnt, ssrc, sdst);

  // ---- weight prep ----
  wcast_k<<<7, 256, 0, stream>>>(Win_exp, Win_mat, Wsrc_em, Wsrc_me,
                                 Wsrc_em + 16384, Wsrc_me + 16384, Wr1, Wt);
  vfold4_k<<<4, 512, 0, stream>>>(Wdst_em, adst_em, Wdst_me, adst_me, Vb);

  const int* offs_em = offs;
  const int* offs_me = offs + NM_N;

  // ---- input projections (paired): he0->bufA (+me0 ald), hm0->bufB (+em0 ald)
  {
    GArgs a = {nullptr, x_exp, Wt, bin_exp, bufA, nullptr, nullptr, Vb + 512, aldE, NE_N, 0};
    GArgs b = {nullptr, x_mat, Wt + 16384, bin_mat, bufB, nullptr, nullptr, Vb, aldM, NM_N, 0};
    mgemm2_k<<<2 * gGemm, 256, 0, stream>>>(a, b, gGemm);
  }
  // ---- layer 1 src GEMMs (paired): hs_em->bufC (+alsE), hs_me->bufD (+alsM)
  {
    GArgs a = {bufA, nullptr, Wt + 2 * 16384, nullptr, bufC, asrc_em, alsE, nullptr, nullptr, NE_N, 0};
    GArgs b = {bufB, nullptr, Wt + 3 * 16384, nullptr, bufD, asrc_me, alsM, nullptr, nullptr, NM_N, 0};
    mgemm2_k<<<2 * gGemm, 256, 0, stream>>>(a, b, gGemm);
  }
  // ---- layer 1 edge weights + aggregation (paired) ----
  pexp_k<<<gE2, 256, 0, stream>>>(ssrc, sdst, alsE, aldM, alsM, aldE, p);
  {
    AArgs a = {bufC, p, offs_em, ssrc, b_em, nullptr, bufA, Vb + 1024, aldM, NM_N};  // hm1
    AArgs b = {bufD, p, offs_me, ssrc, b_me, nullptr, bufB, Vb + 1536, aldE, NE_N};  // he1
    agg2_k<<<2 * gWave, 256, 0, stream>>>(a, b, gWave);
  }
  // ---- layer 2 src GEMMs (paired): from he1=bufB, hm1=bufA ----
  {
    GArgs a = {bufB, nullptr, Wt + 4 * 16384, nullptr, bufC, asrc_em + 128, alsE, nullptr, nullptr, NE_N, 0};
    GArgs b = {bufA, nullptr, Wt + 5 * 16384, nullptr, bufD, asrc_me + 128, alsM, nullptr, nullptr, NM_N, 0};
    mgemm2_k<<<2 * gGemm, 256, 0, stream>>>(a, b, gGemm);
  }
  // ---- layer 2 edge weights + aggregation (paired) ----
  pexp_k<<<gE2, 256, 0, stream>>>(ssrc, sdst, alsE, aldM, alsM, aldE, p);
  {
    AArgs a = {bufC, p, offs_em, ssrc, b_em + 128, hmO, nullptr, nullptr, nullptr, NM_N};
    AArgs b = {bufD, p, offs_me, ssrc, b_me + 128, heO, bufA, nullptr, nullptr, NE_N};  // he2->bufA
    agg2_k<<<2 * gWave, 256, 0, stream>>>(a, b, gWave);
  }
  // ---- regressor ----
  {
    GArgs a = {bufA, nullptr, Wt + 6 * 16384, br1, bufB, nullptr, nullptr, nullptr, nullptr, NE_N, 1};
    mgemm2_k<<<gGemm, 256, 0, stream>>>(a, a, gGemm);
  }
  regfuse_k<<<(NE_N + 63) / 64, 256, 0, stream>>>(bufB, Wr2, br2, Wr3, br3,
                                                  pred, NE_N);
}

// Round 7
// 413.580 us; speedup vs baseline: 1.1855x; 1.1855x over previous
//
#include <hip/hip_runtime.h>
#include <hip/hip_bf16.h>
#include <math.h>

#define NE_N 50000
#define NM_N 50000
#define NEDGE 500000

typedef __attribute__((ext_vector_type(8))) short bf16x8;
typedef __attribute__((ext_vector_type(4))) float f32x4;

__device__ __forceinline__ ushort f2bf(float f) {
  uint u = __float_as_uint(f);
  u += 0x7fffu + ((u >> 16) & 1u);   // RNE
  return (ushort)(u >> 16);
}
__device__ __forceinline__ float bfl(uint u) { return __uint_as_float(u << 16); }
__device__ __forceinline__ float bfh(uint u) { return __uint_as_float(u & 0xffff0000u); }

// ---- composite weights: Wt[b] = bf16T(Win @ Wsrc), bc[b] = bin @ Wsrc ----
__global__ __launch_bounds__(256) void cmm_k(const float* WinE, const float* binE,
    const float* WsE, const float* WinM, const float* binM, const float* WsM,
    ushort* __restrict__ Wt, float* __restrict__ bc) {
  __shared__ float sB[128][128];
  const int b = blockIdx.x;
  const float* A   = b ? WinM : WinE;
  const float* bin = b ? binM : binE;
  const float* B   = b ? WsM  : WsE;
  const int tid = threadIdx.x;
  for (int i = tid; i < 16384; i += 256) sB[i >> 7][i & 127] = B[i];
  __syncthreads();
  const int r = tid >> 1, c0 = (tid & 1) * 64;
  float acc[64];
#pragma unroll
  for (int j = 0; j < 64; ++j) acc[j] = 0.f;
  for (int k = 0; k < 128; ++k) {
    float a = A[r * 128 + k];
#pragma unroll
    for (int j = 0; j < 64; ++j) acc[j] = fmaf(a, sB[k][c0 + j], acc[j]);
  }
  ushort* o = Wt + (size_t)b * 16384;
  for (int j = 0; j < 64; ++j) o[(c0 + j) * 128 + r] = f2bf(acc[j]);
  if (tid < 128) {
    float s = 0.f;
    for (int k = 0; k < 128; ++k) s = fmaf(bin[k], sB[k][tid], s);
    bc[b * 128 + tid] = s;
  }
}

// ---- cast + transpose 3 plain GEMM weights into Wt[2..4] ------------------
__global__ __launch_bounds__(256) void wcast3_k(const float* W0, const float* W1,
                                                const float* W2, ushort* __restrict__ Wt) {
  __shared__ float T[128][129];
  const float* W = (blockIdx.x == 0) ? W0 : (blockIdx.x == 1) ? W1 : W2;
  int tid = threadIdx.x;
  for (int i = tid; i < 16384; i += 256) T[i >> 7][i & 127] = W[i];
  __syncthreads();
  uint* o = (uint*)(Wt + (size_t)(2 + blockIdx.x) * 16384);
  for (int i = tid; i < 8192; i += 256) {
    int n = i >> 6, k2 = (i & 63) << 1;
    o[i] = (uint)f2bf(T[k2][n]) | ((uint)f2bf(T[k2 + 1][n]) << 16);
  }
}

// ---- V[k,h] folds for the 4 dst attention vectors -------------------------
__global__ void vfold4_k(const float* __restrict__ Wem, const float* __restrict__ aem,
                         const float* __restrict__ Wme, const float* __restrict__ ame,
                         float* __restrict__ Vbase) {
  int idx = blockIdx.x;   // 0=em0 1=me0 2=em1 3=me1
  int layer = idx >> 1, et = idx & 1;
  const float* W = (et ? Wme : Wem) + layer * 16384;
  const float* a = (et ? ame : aem) + layer * 128;
  float* V = Vbase + idx * 512;
  int t = threadIdx.x;  // 512
  int k = t >> 2, h = t & 3;
  float s = 0.f;
#pragma unroll
  for (int d = 0; d < 32; ++d) s += W[k * 128 + h * 32 + d] * a[h * 32 + d];
  V[k * 4 + h] = s;
}

// ---- composite dst-logit maps: VcT = bf16((Win @ v0)^T), bias4 = bin @ v0 -
__global__ __launch_bounds__(512) void smallprep_k(const float* WinE, const float* binE,
    const float* WinM, const float* binM, const float* __restrict__ Vb,
    ushort* __restrict__ VcTa, ushort* __restrict__ VcTb, float* __restrict__ bias4) {
  const int b = blockIdx.x;           // 0: Win_exp x v0_me0 -> VcTa; 1: Win_mat x v0_em0 -> VcTb
  const float* Win = b ? WinM : WinE;
  const float* bin = b ? binM : binE;
  const float* v0  = b ? Vb : Vb + 512;
  ushort* VcT = b ? VcTb : VcTa;
  int t = threadIdx.x;
  int c = t & 3, k = t >> 2;
  float s = 0.f;
  for (int j = 0; j < 128; ++j) s = fmaf(Win[k * 128 + j], v0[j * 4 + c], s);
  VcT[c * 128 + k] = f2bf(s);
  for (int z = t; z < 12 * 128; z += 512) VcT[512 + z] = 0;  // pad rows 4..15
  if (t < 4) {
    float s2 = 0.f;
    for (int j = 0; j < 128; ++j) s2 = fmaf(bin[j], v0[j * 4 + t], s2);
    bias4[b * 4 + t] = s2;
  }
}

// ---- MFMA bf16 GEMM: Cb[M,128](bf16) = A[M,128] @ Wt^T (+bias)(+relu)
//      A: bf16 (A) or fp32 (Af, cast during staging)
//      epilogues: als (post-bias, aV), composite ald4 via extra MFMA (VcT)
__global__ __launch_bounds__(256) void mgemm_k(const ushort* __restrict__ A,
    const float* __restrict__ Af,
    const ushort* __restrict__ Wt, const float* __restrict__ bias,
    ushort* __restrict__ Cb, int M, int act,
    const float* __restrict__ aV, float* __restrict__ alsOut,
    const ushort* __restrict__ VcT, const float* __restrict__ bias4,
    float* __restrict__ ald4Out) {
  __shared__ char smem[69632];  // 32KB A | 32KB W | 4KB VcT, XOR-swizzled
  char* sA = smem;
  char* sW = smem + 32768;
  char* sV = smem + 65536;
  const int tid = threadIdx.x;
  const int row0 = blockIdx.x * 128;
#pragma unroll
  for (int i = 0; i < 8; ++i) {
    int l = (tid + i * 256) << 4;
    int rl = l >> 8;
    int rg = row0 + rl; rg = rg < M ? rg : M - 1;
    if (Af) {
      int c0f = (l & 255) >> 1;
      float4 a = *(const float4*)&Af[(size_t)rg * 128 + c0f];
      float4 b = *(const float4*)&Af[(size_t)rg * 128 + c0f + 4];
      ushort r[8] = {f2bf(a.x), f2bf(a.y), f2bf(a.z), f2bf(a.w),
                     f2bf(b.x), f2bf(b.y), f2bf(b.z), f2bf(b.w)};
      *(uint4*)(sA + (l ^ ((rl & 7) << 4))) = *(uint4*)r;
    } else {
      uint4 v = *(const uint4*)((const char*)A + (size_t)rg * 256 + (l & 255));
      *(uint4*)(sA + (l ^ ((rl & 7) << 4))) = v;
    }
    uint4 w = *(const uint4*)((const char*)Wt + l);
    *(uint4*)(sW + (l ^ ((rl & 7) << 4))) = w;
  }
  if (VcT) {
    int l = tid << 4;  // 4 KB
    int rl = l >> 8;
    uint4 v = *(const uint4*)((const char*)VcT + l);
    *(uint4*)(sV + (l ^ ((rl & 7) << 4))) = v;
  }
  __syncthreads();
  const int lane = tid & 63, wid = tid >> 6;
  const int l15 = lane & 15, lq = lane >> 4;
  const int wm = wid * 32;
  f32x4 acc[2][8];
  f32x4 accd[2];
  {
    f32x4 z = {0.f, 0.f, 0.f, 0.f};
#pragma unroll
    for (int mt = 0; mt < 2; ++mt) {
      accd[mt] = z;
#pragma unroll
      for (int nt = 0; nt < 8; ++nt) acc[mt][nt] = z;
    }
  }
#pragma unroll
  for (int ks = 0; ks < 4; ++ks) {
    int r0r = wm + l15;
    int o0 = (r0r << 8) + (ks << 6) + (lq << 4);
    bf16x8 af0 = *(const bf16x8*)(sA + (o0 ^ ((r0r & 7) << 4)));
    int r1r = r0r + 16;
    int o1 = (r1r << 8) + (ks << 6) + (lq << 4);
    bf16x8 af1 = *(const bf16x8*)(sA + (o1 ^ ((r1r & 7) << 4)));
    if (VcT) {
      int ov = (l15 << 8) + (ks << 6) + (lq << 4);
      bf16x8 vf = *(const bf16x8*)(sV + (ov ^ ((l15 & 7) << 4)));
      accd[0] = __builtin_amdgcn_mfma_f32_16x16x32_bf16(af0, vf, accd[0], 0, 0, 0);
      accd[1] = __builtin_amdgcn_mfma_f32_16x16x32_bf16(af1, vf, accd[1], 0, 0, 0);
    }
#pragma unroll
    for (int nt = 0; nt < 8; ++nt) {
      int c = (nt << 4) + l15;
      int ob = (c << 8) + (ks << 6) + (lq << 4);
      bf16x8 bf = *(const bf16x8*)(sW + (ob ^ ((c & 7) << 4)));
      acc[0][nt] = __builtin_amdgcn_mfma_f32_16x16x32_bf16(af0, bf, acc[0][nt], 0, 0, 0);
      acc[1][nt] = __builtin_amdgcn_mfma_f32_16x16x32_bf16(af1, bf, acc[1][nt], 0, 0, 0);
    }
  }
  // bias + act first (als is on FULL hs values)
  float aVv[8], bv[8];
#pragma unroll
  for (int nt = 0; nt < 8; ++nt) {
    int c = (nt << 4) + l15;
    aVv[nt] = aV ? aV[c] : 0.f;
    bv[nt] = bias ? bias[c] : 0.f;
  }
#pragma unroll
  for (int mt = 0; mt < 2; ++mt)
#pragma unroll
    for (int nt = 0; nt < 8; ++nt)
#pragma unroll
      for (int rg = 0; rg < 4; ++rg) {
        float v = acc[mt][nt][rg] + bv[nt];
        if (act) v = fmaxf(v, 0.f);
        acc[mt][nt][rg] = v;
      }
  if (aV) {
#pragma unroll
    for (int mt = 0; mt < 2; ++mt)
#pragma unroll
      for (int rg = 0; rg < 4; ++rg) {
        float p0 = fmaf(acc[mt][0][rg], aVv[0], acc[mt][1][rg] * aVv[1]);
        float p1 = fmaf(acc[mt][2][rg], aVv[2], acc[mt][3][rg] * aVv[3]);
        float p2 = fmaf(acc[mt][4][rg], aVv[4], acc[mt][5][rg] * aVv[5]);
        float p3 = fmaf(acc[mt][6][rg], aVv[6], acc[mt][7][rg] * aVv[7]);
#pragma unroll
        for (int off = 1; off < 16; off <<= 1) {
          p0 += __shfl_xor(p0, off, 64);
          p1 += __shfl_xor(p1, off, 64);
          p2 += __shfl_xor(p2, off, 64);
          p3 += __shfl_xor(p3, off, 64);
        }
        int r = row0 + wm + mt * 16 + lq * 4 + rg;
        if (l15 == 0 && r < M)
          *(float4*)&alsOut[(size_t)r * 4] = make_float4(p0, p1, p2, p3);
      }
  }
  if (VcT) {
    float b4 = (l15 < 4) ? bias4[l15] : 0.f;
#pragma unroll
    for (int mt = 0; mt < 2; ++mt)
#pragma unroll
      for (int rg = 0; rg < 4; ++rg) {
        int r = row0 + wm + mt * 16 + lq * 4 + rg;
        if (l15 < 4 && r < M) ald4Out[(size_t)r * 4 + l15] = accd[mt][rg] + b4;
      }
  }
  // repack bf16 via LDS (swizzled) -> coalesced global stores
  __syncthreads();
#pragma unroll
  for (int mt = 0; mt < 2; ++mt)
#pragma unroll
    for (int nt = 0; nt < 8; ++nt)
#pragma unroll
      for (int rg = 0; rg < 4; ++rg) {
        int r = wm + mt * 16 + lq * 4 + rg;
        int c = (nt << 4) + l15;
        *(ushort*)(sA + ((r << 8) + ((c << 1) ^ ((r & 7) << 4)))) =
            f2bf(acc[mt][nt][rg]);
      }
  __syncthreads();
#pragma unroll
  for (int i = 0; i < 8; ++i) {
    int l = (tid + i * 256) << 4;
    int rl = l >> 8;
    if (row0 + rl < M)
      *(uint4*)((char*)Cb + (size_t)row0 * 256 + l) =
          *(const uint4*)(sA + (l ^ ((rl & 7) << 4)));
  }
}

// ---- unified counting sort over both edge types (100k buckets) ------------
__global__ void hist2_k(const int* __restrict__ de, const int* __restrict__ dm,
                        int* __restrict__ cnt) {
  int e = blockIdx.x * 256 + threadIdx.x;
  if (e < NEDGE) atomicAdd(&cnt[de[e]], 1);
  else if (e < 2 * NEDGE) atomicAdd(&cnt[NM_N + dm[e - NEDGE]], 1);
}

__global__ __launch_bounds__(256) void scanA_k(const int* __restrict__ cnt,
                                               int* __restrict__ offs,
                                               int* __restrict__ sums, int n) {
  __shared__ int ts[256];
  int tid = threadIdx.x;
  int base = blockIdx.x * 4096 + tid * 16;
  int v[16];
  int s = 0;
#pragma unroll
  for (int i = 0; i < 16; ++i) {
    v[i] = (base + i < n) ? cnt[base + i] : 0;
    s += v[i];
  }
  ts[tid] = s;
  __syncthreads();
  for (int off = 1; off < 256; off <<= 1) {
    int t = (tid >= off) ? ts[tid - off] : 0;
    __syncthreads();
    ts[tid] += t;
    __syncthreads();
  }
  int run = ts[tid] - s;
#pragma unroll
  for (int i = 0; i < 16; ++i) {
    if (base + i < n) offs[base + i] = run;
    run += v[i];
  }
  if (tid == 255) sums[blockIdx.x] = ts[255];
}

__global__ void scanB_k(int* __restrict__ sums, int nchunk) {
  if (threadIdx.x == 0) {
    int acc = 0;
    for (int i = 0; i < nchunk; ++i) {
      int t = sums[i];
      sums[i] = acc;
      acc += t;
    }
    sums[nchunk] = acc;
  }
}

__global__ void scanC_k(int* __restrict__ offs, const int* __restrict__ sums, int n) {
  int i = blockIdx.x * blockDim.x + threadIdx.x;
  if (i < n) offs[i] += sums[i >> 12];
  if (i == 0) offs[n] = sums[(n + 4095) >> 12];
}

__global__ void scatter2_k(const int* __restrict__ se, const int* __restrict__ de,
                           const int* __restrict__ sm, const int* __restrict__ dm,
                           const int* __restrict__ offs, int* __restrict__ cur,
                           int* __restrict__ ssrc) {
  int e = blockIdx.x * 256 + threadIdx.x;
  if (e >= 2 * NEDGE) return;
  int s, db;
  if (e < NEDGE) { s = se[e]; db = de[e]; }
  else { s = sm[e - NEDGE]; db = NM_N + dm[e - NEDGE]; }
  int pos = offs[db] + atomicAdd(&cur[db], 1);
  ssrc[pos] = s;
}

// ---- per-dst softmax aggregation (bf16 hs), unshifted exp, 8-wide ---------
__global__ __launch_bounds__(256) void gat_agg_k(const ushort* __restrict__ hs,
    const float* __restrict__ als, const float* __restrict__ ald,
    const int* __restrict__ offs, const int* __restrict__ ssrc,
    const float* __restrict__ bias, float* __restrict__ out,
    ushort* __restrict__ outB, int Ndst,
    const float* __restrict__ Vald, float* __restrict__ aldOut) {
  const int lane = threadIdx.x & 63;
  const int n = (blockIdx.x * 256 + threadIdx.x) >> 6;
  if (n >= Ndst) return;
  const int h = lane >> 4;
  const uint* hsu = (const uint*)hs;
  const float ad = ald[(size_t)n * 4 + h];
  const int i0 = offs[n], i1 = offs[n + 1];
  float den0 = 0.f, den1 = 0.f, acc0 = 0.f, acc1 = 0.f;
  int i = i0;
  for (; i + 8 <= i1; i += 8) {
    int s[8];
#pragma unroll
    for (int k = 0; k < 8; ++k) s[k] = ssrc[i + k];
    float p[8];
#pragma unroll
    for (int k = 0; k < 8; ++k) {
      float e = als[(size_t)s[k] * 4 + h] + ad;
      e = (e > 0.f) ? e : 0.2f * e;
      p[k] = __expf(e);
    }
    uint u[8];
#pragma unroll
    for (int k = 0; k < 8; ++k) u[k] = hsu[(size_t)s[k] * 64 + lane];
#pragma unroll
    for (int k = 0; k < 8; ++k) {
      acc0 = fmaf(p[k], bfl(u[k]), acc0);
      acc1 = fmaf(p[k], bfh(u[k]), acc1);
      if (k & 1) den1 += p[k]; else den0 += p[k];
    }
  }
  for (; i < i1; ++i) {
    int s0 = ssrc[i];
    float e = als[(size_t)s0 * 4 + h] + ad;
    e = (e > 0.f) ? e : 0.2f * e;
    float p0 = __expf(e);
    uint u0 = hsu[(size_t)s0 * 64 + lane];
    acc0 = fmaf(p0, bfl(u0), acc0);
    acc1 = fmaf(p0, bfh(u0), acc1);
    den0 += p0;
  }
  const float inv = 1.f / (den0 + den1 + 1e-16f);
  float r0 = acc0 * inv + bias[2 * lane];
  float r1 = acc1 * inv + bias[2 * lane + 1];
  r0 = (r0 > 0.f) ? r0 : expm1f(r0);  // ELU
  r1 = (r1 > 0.f) ? r1 : expm1f(r1);
  if (out)
    *(float2*)&out[(size_t)n * 128 + 2 * lane] = make_float2(r0, r1);
  if (outB)
    ((uint*)outB)[(size_t)n * 64 + lane] = (uint)f2bf(r0) | ((uint)f2bf(r1) << 16);
  if (Vald) {
    const float4 w0 = *(const float4*)&Vald[(2 * lane) * 4];
    const float4 w1 = *(const float4*)&Vald[(2 * lane + 1) * 4];
    float t0 = fmaf(r0, w0.x, r1 * w1.x);
    float t1 = fmaf(r0, w0.y, r1 * w1.y);
    float t2 = fmaf(r0, w0.z, r1 * w1.z);
    float t3 = fmaf(r0, w0.w, r1 * w1.w);
#pragma unroll
    for (int off = 1; off < 64; off <<= 1) {
      t0 += __shfl_xor(t0, off, 64);
      t1 += __shfl_xor(t1, off, 64);
      t2 += __shfl_xor(t2, off, 64);
      t3 += __shfl_xor(t3, off, 64);
    }
    if (lane == 0)
      *(float4*)&aldOut[(size_t)n * 4] = make_float4(t0, t1, t2, t3);
  }
}

// ---- fused regressor tail: pred = relu(h1(bf16)@W2+b2) @ W3 + b3 ----------
__global__ __launch_bounds__(256) void regfuse_k(const ushort* __restrict__ h1,
    const float* __restrict__ W2, const float* __restrict__ b2,
    const float* __restrict__ W3, const float* __restrict__ b3,
    float* __restrict__ pred, int M) {
  __shared__ float X[64][132];
  const int tid = threadIdx.x;
  const int row0 = blockIdx.x * 64;
#pragma unroll
  for (int i = 0; i < 4; ++i) {
    int q = tid + i * 256;
    int r = q >> 4, c8 = (q & 15) << 3;
    uint4 v = make_uint4(0, 0, 0, 0);
    if (row0 + r < M) v = *(const uint4*)&h1[(size_t)(row0 + r) * 128 + c8];
    X[r][c8 + 0] = bfl(v.x); X[r][c8 + 1] = bfh(v.x);
    X[r][c8 + 2] = bfl(v.y); X[r][c8 + 3] = bfh(v.y);
    X[r][c8 + 4] = bfl(v.z); X[r][c8 + 5] = bfh(v.z);
    X[r][c8 + 6] = bfl(v.w); X[r][c8 + 7] = bfh(v.w);
  }
  __syncthreads();
  const int cg = tid & 15, rq = tid >> 4;
  const int c0 = cg * 4;
  float acc[4][4];
#pragma unroll
  for (int s = 0; s < 4; ++s)
#pragma unroll
    for (int j = 0; j < 4; ++j) acc[s][j] = 0.f;
#pragma unroll 4
  for (int k = 0; k < 128; ++k) {
    float xv[4] = {X[rq][k], X[rq + 16][k], X[rq + 32][k], X[rq + 48][k]};
    float4 w = *(const float4*)&W2[k * 64 + c0];
#pragma unroll
    for (int s = 0; s < 4; ++s) {
      acc[s][0] = fmaf(xv[s], w.x, acc[s][0]);
      acc[s][1] = fmaf(xv[s], w.y, acc[s][1]);
      acc[s][2] = fmaf(xv[s], w.z, acc[s][2]);
      acc[s][3] = fmaf(xv[s], w.w, acc[s][3]);
    }
  }
  float4 bq = *(const float4*)&b2[c0];
  float4 w3 = *(const float4*)&W3[c0];
  float bb[4] = {bq.x, bq.y, bq.z, bq.w};
  float ww[4] = {w3.x, w3.y, w3.z, w3.w};
#pragma unroll
  for (int s = 0; s < 4; ++s) {
    float v = 0.f;
#pragma unroll
    for (int j = 0; j < 4; ++j) v = fmaf(fmaxf(acc[s][j] + bb[j], 0.f), ww[j], v);
    v += __shfl_xor(v, 1, 64);
    v += __shfl_xor(v, 2, 64);
    v += __shfl_xor(v, 4, 64);
    v += __shfl_xor(v, 8, 64);
    int r = row0 + rq + 16 * s;
    if (cg == 0 && r < M) pred[r] = v + b3[0];
  }
}

extern "C" void kernel_launch(void* const* d_in, const int* in_sizes, int n_in,
                              void* d_out, int out_size, void* d_ws, size_t ws_size,
                              hipStream_t stream) {
  const float* x_exp   = (const float*)d_in[0];
  const float* x_mat   = (const float*)d_in[1];
  const int*   ei_em   = (const int*)d_in[2];
  const int*   ei_me   = (const int*)d_in[3];
  const float* Win_exp = (const float*)d_in[4];
  const float* bin_exp = (const float*)d_in[5];
  const float* Win_mat = (const float*)d_in[6];
  const float* bin_mat = (const float*)d_in[7];
  const float* Wsrc_em = (const float*)d_in[8];
  const float* Wdst_em = (const float*)d_in[9];
  const float* asrc_em = (const float*)d_in[10];
  const float* adst_em = (const float*)d_in[11];
  const float* b_em    = (const float*)d_in[12];
  const float* Wsrc_me = (const float*)d_in[13];
  const float* Wdst_me = (const float*)d_in[14];
  const float* asrc_me = (const float*)d_in[15];
  const float* adst_me = (const float*)d_in[16];
  const float* b_me    = (const float*)d_in[17];
  const float* Wr1     = (const float*)d_in[18];
  const float* br1     = (const float*)d_in[19];
  const float* Wr2     = (const float*)d_in[20];
  const float* br2     = (const float*)d_in[21];
  const float* Wr3     = (const float*)d_in[22];
  const float* br3     = (const float*)d_in[23];

  float* pred = (float*)d_out;
  float* heO  = pred + NE_N;
  float* hmO  = heO + (size_t)NE_N * 128;

  ushort* bufA  = (ushort*)d_ws;                  // 4 x 12.8MB bf16 buffers
  ushort* bufB  = bufA + (size_t)6400000;
  ushort* bufC  = bufB + (size_t)6400000;
  ushort* bufD  = bufC + (size_t)6400000;
  ushort* Wt    = bufD + (size_t)6400000;         // 5 x 16384 bf16
  ushort* VcTa  = Wt + 5 * 16384;                 // 16x128 bf16
  ushort* VcTb  = VcTa + 2048;
  float*  bc    = (float*)(VcTb + 2048);          // 2 x 128 composite biases
  float*  bias4 = bc + 256;                       // 2 x 4
  float*  alsE  = bias4 + 8;
  float*  alsM  = alsE + 200000;
  float*  aldE  = alsM + 200000;
  float*  aldM  = aldE + 200000;
  float*  Vb    = aldM + 200000;                  // 4 x 512 fp32 v0 folds
  int*    sums  = (int*)(Vb + 2048);              // 32
  int*    cnt   = sums + 32;                      // 100k
  int*    offs  = cnt + 100000;                   // 100001
  int*    ssrc  = offs + 100001;                  // 1M

  const int* se = ei_em;
  const int* de = ei_em + NEDGE;
  const int* sm = ei_me;
  const int* dm = ei_me + NEDGE;

  const int gE2 = (2 * NEDGE + 255) / 256;
  const int gWave = (NE_N + 3) / 4;
  const int gGemm = (NE_N + 127) / 128;
  const int nChunk = (100000 + 4095) / 4096;

  // ---- unified counting sort (both edge types, 100k buckets) ----
  hipMemsetAsync(cnt, 0, 100000 * sizeof(int), stream);
  hist2_k<<<gE2, 256, 0, stream>>>(de, dm, cnt);
  scanA_k<<<nChunk, 256, 0, stream>>>(cnt, offs, sums, 100000);
  scanB_k<<<1, 64, 0, stream>>>(sums, nChunk);
  scanC_k<<<(100000 + 255) / 256, 256, 0, stream>>>(offs, sums, 100000);
  hipMemsetAsync(cnt, 0, 100000 * sizeof(int), stream);
  scatter2_k<<<gE2, 256, 0, stream>>>(se, de, sm, dm, offs, cnt, ssrc);

  // ---- weight prep ----
  cmm_k<<<2, 256, 0, stream>>>(Win_exp, bin_exp, Wsrc_em, Win_mat, bin_mat,
                               Wsrc_me, Wt, bc);                  // Wt[0], Wt[1]
  wcast3_k<<<3, 256, 0, stream>>>(Wsrc_em + 16384, Wsrc_me + 16384, Wr1, Wt);
  vfold4_k<<<4, 512, 0, stream>>>(Wdst_em, adst_em, Wdst_me, adst_me, Vb);
  smallprep_k<<<2, 512, 0, stream>>>(Win_exp, bin_exp, Win_mat, bin_mat, Vb,
                                     VcTa, VcTb, bias4);

  const int* offs_em = offs;
  const int* offs_me = offs + NM_N;

  // ---- layer 1 composite GEMMs: x -> hs (+als, +composite ald4) ----
  mgemm_k<<<gGemm, 256, 0, stream>>>(nullptr, x_exp, Wt, bc, bufC, NE_N, 0,
                                     asrc_em, alsE, VcTa, bias4, aldE);
  mgemm_k<<<gGemm, 256, 0, stream>>>(nullptr, x_mat, Wt + 16384, bc + 128, bufD,
                                     NM_N, 0, asrc_me, alsM, VcTb, bias4 + 4, aldM);

  // ---- layer 1 aggregations ----
  gat_agg_k<<<gWave, 256, 0, stream>>>(bufC, alsE, aldM, offs_em, ssrc, b_em,
                                       nullptr, bufA, NM_N, Vb + 1024, aldM);  // hm1
  gat_agg_k<<<gWave, 256, 0, stream>>>(bufD, alsM, aldE, offs_me, ssrc, b_me,
                                       nullptr, bufB, NE_N, Vb + 1536, aldE);  // he1

  // ---- layer 2 GEMMs ----
  mgemm_k<<<gGemm, 256, 0, stream>>>(bufB, nullptr, Wt + 2 * 16384, nullptr, bufC,
                                     NE_N, 0, asrc_em + 128, alsE,
                                     nullptr, nullptr, nullptr);
  mgemm_k<<<gGemm, 256, 0, stream>>>(bufA, nullptr, Wt + 3 * 16384, nullptr, bufD,
                                     NM_N, 0, asrc_me + 128, alsM,
                                     nullptr, nullptr, nullptr);

  // ---- layer 2 aggregations ----
  gat_agg_k<<<gWave, 256, 0, stream>>>(bufC, alsE, aldM, offs_em, ssrc,
                                       b_em + 128, hmO, nullptr, NM_N,
                                       nullptr, nullptr);
  gat_agg_k<<<gWave, 256, 0, stream>>>(bufD, alsM, aldE, offs_me, ssrc,
                                       b_me + 128, heO, bufA, NE_N,
                                       nullptr, nullptr);

  // ---- regressor ----
  mgemm_k<<<gGemm, 256, 0, stream>>>(bufA, nullptr, Wt + 4 * 16384, br1, bufB,
                                     NE_N, 1, nullptr, nullptr,
                                     nullptr, nullptr, nullptr);
  regfuse_k<<<(NE_N + 63) / 64, 256, 0, stream>>>(bufB, Wr2, br2, Wr3, br3,
                                                  pred, NE_N);
}